// Round 1
// baseline (118.020 us; speedup 1.0000x reference)
//
#include <hip/hip_runtime.h>
#include <math.h>

#define NN 4
#define LL 4096
#define HH 8
#define EE 64
#define CHK 128
#define SUB 64
#define NCH (LL/CHK)      // 32 chunks per (n,h)
#define NG (NN*HH*NCH)    // 1024 blocks
#define EPSF 1e-6f

__device__ __forceinline__ float phi_map(float x) {
  // elu(x)+1
  return x > 0.0f ? x + 1.0f : __expf(x);
}

// ---------------- Kernel 1: per-(n,h,chunk) S_c = K^T V over 128 rows, ksum_c = colsum(K)
__global__ __launch_bounds__(256) void k_chunksums(
    const float* __restrict__ Kg, const float* __restrict__ Vg,
    const float* __restrict__ KLg, float* __restrict__ Sg, float* __restrict__ KsumG)
{
  __shared__ float sk[CHK][68];
  __shared__ float sv[CHK][64];
  const int g = blockIdx.x;
  const int c = g % NCH;
  const int nh = g / NCH;
  const int h = nh % HH;
  const int n = nh / HH;
  const int l0 = c * CHK;
  const int t = threadIdx.x;

  #pragma unroll
  for (int it = 0; it < 8; ++it) {
    int f = t + 256 * it;           // float4 index 0..2047
    int r = f >> 4;
    int c4 = (f & 15) << 2;
    size_t gb = (((size_t)n * LL + (size_t)(l0 + r)) * HH + h) * EE + c4;
    float4 kk = *(const float4*)(Kg + gb);
    float4 vv = *(const float4*)(Vg + gb);
    float klr = KLg[n * LL + l0 + r];
    sk[r][c4 + 0] = phi_map(kk.x) * klr;
    sk[r][c4 + 1] = phi_map(kk.y) * klr;
    sk[r][c4 + 2] = phi_map(kk.z) * klr;
    sk[r][c4 + 3] = phi_map(kk.w) * klr;
    *(float4*)&sv[r][c4] = vv;
  }
  __syncthreads();

  const int e = t >> 2;
  const int mq = t & 3;
  float acc[16];
  #pragma unroll
  for (int j = 0; j < 16; ++j) acc[j] = 0.0f;
  float ks = 0.0f;
  for (int d = 0; d < CHK; ++d) {
    float kv = sk[d][e];
    ks += kv;
    const float4* vp4 = (const float4*)&sv[d][mq * 16];
    #pragma unroll
    for (int j4 = 0; j4 < 4; ++j4) {
      float4 v4 = vp4[j4];
      acc[4*j4+0] += kv * v4.x;
      acc[4*j4+1] += kv * v4.y;
      acc[4*j4+2] += kv * v4.z;
      acc[4*j4+3] += kv * v4.w;
    }
  }
  float* sp = Sg + (size_t)g * 4096 + e * 64 + mq * 16;
  #pragma unroll
  for (int j4 = 0; j4 < 4; ++j4)
    *(float4*)(sp + 4*j4) = make_float4(acc[4*j4], acc[4*j4+1], acc[4*j4+2], acc[4*j4+3]);
  if (mq == 0) KsumG[(size_t)g * 64 + e] = ks;
}

// ---------------- Kernel 2: exclusive prefix over the 32 chunks of each (n,h), in place
__global__ __launch_bounds__(256) void k_prefix(float* __restrict__ Sg, float* __restrict__ KsumG)
{
  const int bid = blockIdx.x;       // nh*16 + strip
  const int nh = bid >> 4;
  const int strip = bid & 15;
  const int t = threadIdx.x;
  const int entry = strip * 256 + t;
  float run = 0.0f;
  for (int c = 0; c < NCH; ++c) {
    size_t base = ((size_t)nh * NCH + c) * 4096 + entry;
    float v = Sg[base];
    Sg[base] = run;
    run += v;
  }
  if (strip == 0 && t < 64) {
    float krun = 0.0f;
    for (int c = 0; c < NCH; ++c) {
      size_t kb = ((size_t)nh * NCH + c) * 64 + t;
      float v = KsumG[kb];
      KsumG[kb] = krun;
      krun += v;
    }
  }
}

// ---------------- Kernel 3: per-chunk output (two 64-row sub-chunks)
__global__ __launch_bounds__(256) void k_pass2(
    const float* __restrict__ Qg, const float* __restrict__ Kg,
    const float* __restrict__ Vg, const float* __restrict__ KLg,
    const float* __restrict__ Sg, const float* __restrict__ KsumG,
    float* __restrict__ Og)
{
  __shared__ float sA[SUB][68];   // holds Q, then V
  __shared__ float sK[SUB][68];
  __shared__ float sAt[SUB][68];  // tril attn
  __shared__ float sS[EE][64];    // running KV state
  __shared__ float sKs[EE];       // running K colsum

  const int g = blockIdx.x;
  const int c = g % NCH;
  const int nh = g / NCH;
  const int h = nh % HH;
  const int n = nh / HH;
  const int t = threadIdx.x;

  {
    const float* sp = Sg + (size_t)g * 4096;
    float* dst = &sS[0][0];
    #pragma unroll
    for (int jj = 0; jj < 16; ++jj) dst[t + 256*jj] = sp[t + 256*jj];
    if (t < 64) sKs[t] = KsumG[(size_t)g * 64 + t];
  }

  const int r = t >> 2;     // row within sub-chunk
  const int mq = t & 3;     // 16-wide m slice

  for (int s = 0; s < 2; ++s) {
    const int l0 = c * CHK + s * SUB;

    // load phi(Q) -> sA, phi(K)*kl -> sK
    #pragma unroll
    for (int it = 0; it < 4; ++it) {
      int f = t + 256 * it;
      int rr = f >> 4;
      int c4 = (f & 15) << 2;
      size_t gb = (((size_t)n * LL + (size_t)(l0 + rr)) * HH + h) * EE + c4;
      float4 qq = *(const float4*)(Qg + gb);
      float4 kk = *(const float4*)(Kg + gb);
      float klr = KLg[n * LL + l0 + rr];
      sA[rr][c4+0] = phi_map(qq.x);
      sA[rr][c4+1] = phi_map(qq.y);
      sA[rr][c4+2] = phi_map(qq.z);
      sA[rr][c4+3] = phi_map(qq.w);
      sK[rr][c4+0] = phi_map(kk.x) * klr;
      sK[rr][c4+1] = phi_map(kk.y) * klr;
      sK[rr][c4+2] = phi_map(kk.z) * klr;
      sK[rr][c4+3] = phi_map(kk.w) * klr;
    }
    __syncthreads();

    float acc[16];
    #pragma unroll
    for (int j = 0; j < 16; ++j) acc[j] = 0.0f;
    float den = 0.0f;

    // inter: acc[m] += q[r]·S[:,m];  den += q[r]·ksum_prefix
    for (int e = 0; e < EE; ++e) {
      float qv = sA[r][e];
      den += qv * sKs[e];
      const float4* sp4 = (const float4*)&sS[e][mq*16];
      #pragma unroll
      for (int j4 = 0; j4 < 4; ++j4) {
        float4 s4 = sp4[j4];
        acc[4*j4+0] += qv * s4.x;
        acc[4*j4+1] += qv * s4.y;
        acc[4*j4+2] += qv * s4.z;
        acc[4*j4+3] += qv * s4.w;
      }
    }

    // attn: thread owns row r, columns d = mq + 4j (j=0..15)
    {
      float a2[16];
      #pragma unroll
      for (int j = 0; j < 16; ++j) a2[j] = 0.0f;
      for (int e4 = 0; e4 < EE/4; ++e4) {
        float4 q4 = *(const float4*)&sA[r][4*e4];
        #pragma unroll
        for (int j = 0; j < 16; ++j) {
          float4 k4 = *(const float4*)&sK[mq + 4*j][4*e4];
          a2[j] += q4.x*k4.x + q4.y*k4.y + q4.z*k4.z + q4.w*k4.w;
        }
      }
      float asum = 0.0f;
      #pragma unroll
      for (int j = 0; j < 16; ++j) {
        int d = mq + 4*j;
        float av = (d <= r) ? a2[j] : 0.0f;
        sAt[r][d] = av;
        asum += av;
      }
      asum += __shfl_xor(asum, 1);
      asum += __shfl_xor(asum, 2);
      den += asum;
    }
    __syncthreads();

    // V -> sA (Q is dead now)
    #pragma unroll
    for (int it = 0; it < 4; ++it) {
      int f = t + 256 * it;
      int rr = f >> 4;
      int c4 = (f & 15) << 2;
      size_t gb = (((size_t)n * LL + (size_t)(l0 + rr)) * HH + h) * EE + c4;
      *(float4*)&sA[rr][c4] = *(const float4*)(Vg + gb);
    }
    __syncthreads();

    // intra: acc[m] += sum_{d<=r} attn[r][d] * v[d][m]
    for (int d = 0; d <= r; ++d) {
      float av = sAt[r][d];
      const float4* vp4 = (const float4*)&sA[d][mq*16];
      #pragma unroll
      for (int j4 = 0; j4 < 4; ++j4) {
        float4 v4 = vp4[j4];
        acc[4*j4+0] += av * v4.x;
        acc[4*j4+1] += av * v4.y;
        acc[4*j4+2] += av * v4.z;
        acc[4*j4+3] += av * v4.w;
      }
    }

    float inv = 1.0f / (den + EPSF);
    size_t ob = (((size_t)n * LL + (size_t)(l0 + r)) * HH + h) * EE + mq * 16;
    #pragma unroll
    for (int j4 = 0; j4 < 4; ++j4)
      *(float4*)(Og + ob + 4*j4) =
        make_float4(acc[4*j4]*inv, acc[4*j4+1]*inv, acc[4*j4+2]*inv, acc[4*j4+3]*inv);

    if (s == 0) {
      // advance running state by this sub-chunk: sS += k^T v, sKs += colsum(k)
      const int e = r;
      float up[16];
      #pragma unroll
      for (int j = 0; j < 16; ++j) up[j] = 0.0f;
      float ks2 = 0.0f;
      for (int d = 0; d < SUB; ++d) {
        float kv = sK[d][e];
        ks2 += kv;
        const float4* vp4 = (const float4*)&sA[d][mq*16];
        #pragma unroll
        for (int j4 = 0; j4 < 4; ++j4) {
          float4 v4 = vp4[j4];
          up[4*j4+0] += kv * v4.x;
          up[4*j4+1] += kv * v4.y;
          up[4*j4+2] += kv * v4.z;
          up[4*j4+3] += kv * v4.w;
        }
      }
      #pragma unroll
      for (int j = 0; j < 16; ++j) sS[e][mq*16 + j] += up[j];
      if (mq == 0) sKs[e] += ks2;
      __syncthreads();
    }
  }
}

extern "C" void kernel_launch(void* const* d_in, const int* in_sizes, int n_in,
                              void* d_out, int out_size, void* d_ws, size_t ws_size,
                              hipStream_t stream) {
  const float* Qg  = (const float*)d_in[0];
  const float* Kg  = (const float*)d_in[1];
  const float* Vg  = (const float*)d_in[2];
  const float* KLg = (const float*)d_in[3];
  float* Og = (float*)d_out;

  float* Sg    = (float*)d_ws;                                    // NG * 64*64 floats = 16 MB
  float* KsumG = (float*)((char*)d_ws + (size_t)NG * 4096 * 4);   // NG * 64 floats = 256 KB

  hipLaunchKernelGGL(k_chunksums, dim3(NG), dim3(256), 0, stream, Kg, Vg, KLg, Sg, KsumG);
  hipLaunchKernelGGL(k_prefix, dim3(NN*HH*16), dim3(256), 0, stream, Sg, KsumG);
  hipLaunchKernelGGL(k_pass2, dim3(NG), dim3(256), 0, stream, Qg, Kg, Vg, KLg, Sg, KsumG, Og);
}

// Round 2
// 71.366 us; speedup vs baseline: 1.6537x; 1.6537x over previous
//
#include <hip/hip_runtime.h>
#include <math.h>

#define NN 4
#define LL 4096
#define HH 8
#define EE 64
#define CHK 128
#define SUB 64
#define NCH (LL/CHK)      // 32 chunks per (n,h)
#define NG (NN*HH*NCH)    // 1024 blocks
#define EPSF 1e-6f

typedef float f32x4 __attribute__((ext_vector_type(4)));
typedef __bf16 bf16x8 __attribute__((ext_vector_type(8)));

__device__ __forceinline__ float phi_map(float x) {
  return x > 0.0f ? x + 1.0f : __expf(x);
}

#define MFMA(a, b, c) __builtin_amdgcn_mfma_f32_16x16x32_bf16((a), (b), (c), 0, 0, 0)

// ---------------- Kernel 1: per-(n,h,chunk) S_c^T = V^T K  (i.e. SgT[m][e] = sum_d K[d][e]V[d][m])
__global__ __launch_bounds__(256) void k_chunksums(
    const float* __restrict__ Kg, const float* __restrict__ Vg,
    const float* __restrict__ KLg, float* __restrict__ SgT, float* __restrict__ KsumG)
{
  __shared__ float sk[CHK][68];
  __shared__ float sv[CHK][64];
  const int g = blockIdx.x;
  const int c = g % NCH;
  const int nh = g / NCH;
  const int h = nh % HH;
  const int n = nh / HH;
  const int l0 = c * CHK;
  const int t = threadIdx.x;

  #pragma unroll
  for (int it = 0; it < 8; ++it) {
    int f = t + 256 * it;           // float4 index 0..2047
    int r = f >> 4;
    int c4 = (f & 15) << 2;
    size_t gb = (((size_t)n * LL + (size_t)(l0 + r)) * HH + h) * EE + c4;
    float4 kk = *(const float4*)(Kg + gb);
    float4 vv = *(const float4*)(Vg + gb);
    float klr = KLg[n * LL + l0 + r];
    sk[r][c4 + 0] = phi_map(kk.x) * klr;
    sk[r][c4 + 1] = phi_map(kk.y) * klr;
    sk[r][c4 + 2] = phi_map(kk.z) * klr;
    sk[r][c4 + 3] = phi_map(kk.w) * klr;
    *(float4*)&sv[r][c4] = vv;
  }
  __syncthreads();

  // thread owns (m = t>>2, eq = t&3): SgT[m][eq*16 .. +15]
  const int m = t >> 2;
  const int eq = t & 3;
  float acc[16];
  #pragma unroll
  for (int j = 0; j < 16; ++j) acc[j] = 0.0f;
  for (int d = 0; d < CHK; ++d) {
    float vv = sv[d][m];
    const float4* kp4 = (const float4*)&sk[d][eq * 16];
    #pragma unroll
    for (int j4 = 0; j4 < 4; ++j4) {
      float4 k4 = kp4[j4];
      acc[4*j4+0] += vv * k4.x;
      acc[4*j4+1] += vv * k4.y;
      acc[4*j4+2] += vv * k4.z;
      acc[4*j4+3] += vv * k4.w;
    }
  }
  float* sp = SgT + (size_t)g * 4096 + m * 64 + eq * 16;
  #pragma unroll
  for (int j4 = 0; j4 < 4; ++j4)
    *(float4*)(sp + 4*j4) = make_float4(acc[4*j4], acc[4*j4+1], acc[4*j4+2], acc[4*j4+3]);

  // column sums of K (per e)
  if (t < 64) {
    float ks = 0.0f;
    for (int d = 0; d < CHK; ++d) ks += sk[d][t];
    KsumG[(size_t)g * 64 + t] = ks;
  }
}

// ---------------- Kernel 2: exclusive prefix over the 32 chunks of each (n,h), in place
__global__ __launch_bounds__(256) void k_prefix(float* __restrict__ Sg, float* __restrict__ KsumG)
{
  const int bid = blockIdx.x;       // nh*16 + strip
  const int nh = bid >> 4;
  const int strip = bid & 15;
  const int t = threadIdx.x;
  const int entry = strip * 256 + t;
  float run = 0.0f;
  for (int c = 0; c < NCH; ++c) {
    size_t base = ((size_t)nh * NCH + c) * 4096 + entry;
    float v = Sg[base];
    Sg[base] = run;
    run += v;
  }
  if (strip == 0 && t < 64) {
    float krun = 0.0f;
    for (int c = 0; c < NCH; ++c) {
      size_t kb = ((size_t)nh * NCH + c) * 64 + t;
      float v = KsumG[kb];
      KsumG[kb] = krun;
      krun += v;
    }
  }
}

// ---------------- Kernel 3: per-chunk output via bf16 MFMA (two 64-row sub-chunks)
__global__ __launch_bounds__(256) void k_pass2(
    const float* __restrict__ Qg, const float* __restrict__ Kg,
    const float* __restrict__ Vg, const float* __restrict__ KLg,
    const float* __restrict__ SgT, const float* __restrict__ KsumG,
    float* __restrict__ Og)
{
  __shared__ __bf16 sQ[64][72];        // phi(Q) row-major [row][e]
  __shared__ __bf16 sK[2][64][72];     // phi(K)*kl row-major [row][e], per sub
  __shared__ __bf16 sVt[2][64][72];    // V transposed [m][d], per sub
  __shared__ __bf16 sSt[80][72];       // S^T [m][e]; row 64 = ksum_prefix; rows 65-79 zero
  __shared__ __bf16 sAt[4][16][72];    // per-wave attn rows [qrow][d]

  const int g = blockIdx.x;
  const int c = g % NCH;
  const int nh = g / NCH;
  const int h = nh % HH;
  const int n = nh / HH;
  const int t = threadIdx.x;
  const int w = t >> 6;
  const int lane = t & 63;
  const int lg = lane >> 4;     // 4-row group
  const int li = lane & 15;     // col-within-tile / A-row

  // ---- load S^T prefix (fp32 -> bf16) ----
  {
    const float* sp = SgT + (size_t)g * 4096;
    #pragma unroll
    for (int jj = 0; jj < 4; ++jj) {
      int f4 = t + 256 * jj;           // float4 unit 0..1023
      int m = f4 >> 4;
      int e0 = (f4 & 15) << 2;
      float4 s4 = *(const float4*)(sp + (size_t)f4 * 4);
      __bf16* dst = &sSt[m][e0];
      dst[0] = (__bf16)s4.x; dst[1] = (__bf16)s4.y;
      dst[2] = (__bf16)s4.z; dst[3] = (__bf16)s4.w;
    }
    if (t < 64) sSt[64][t] = (__bf16)KsumG[(size_t)g * 64 + t];
    for (int i = t; i < 15 * 72; i += 256) sSt[65 + i / 72][i % 72] = (__bf16)0.0f;
  }

  for (int s = 0; s < 2; ++s) {
    const int l0 = c * CHK + s * SUB;

    // ---- load phi(Q), phi(K)*kl, V^T for this sub ----
    #pragma unroll
    for (int it = 0; it < 4; ++it) {
      int f = t + 256 * it;
      int rr = f >> 4;
      int c4 = (f & 15) << 2;
      size_t gb = (((size_t)n * LL + (size_t)(l0 + rr)) * HH + h) * EE + c4;
      float4 qq = *(const float4*)(Qg + gb);
      float4 kk = *(const float4*)(Kg + gb);
      float4 vv = *(const float4*)(Vg + gb);
      float klr = KLg[n * LL + l0 + rr];
      __bf16* qd = &sQ[rr][c4];
      qd[0] = (__bf16)phi_map(qq.x); qd[1] = (__bf16)phi_map(qq.y);
      qd[2] = (__bf16)phi_map(qq.z); qd[3] = (__bf16)phi_map(qq.w);
      __bf16* kd = &sK[s][rr][c4];
      kd[0] = (__bf16)(phi_map(kk.x) * klr); kd[1] = (__bf16)(phi_map(kk.y) * klr);
      kd[2] = (__bf16)(phi_map(kk.z) * klr); kd[3] = (__bf16)(phi_map(kk.w) * klr);
      sVt[s][c4 + 0][rr] = (__bf16)vv.x;
      sVt[s][c4 + 1][rr] = (__bf16)vv.y;
      sVt[s][c4 + 2][rr] = (__bf16)vv.z;
      sVt[s][c4 + 3][rr] = (__bf16)vv.w;
    }
    __syncthreads();

    // ---- A fragments of Q (wave's 16 rows) ----
    const int arow = 16 * w + li;
    bf16x8 aQ0 = *(const bf16x8*)&sQ[arow][8 * lg];
    bf16x8 aQ1 = *(const bf16x8*)&sQ[arow][32 + 8 * lg];

    f32x4 acc[4];
    #pragma unroll
    for (int nt = 0; nt < 4; ++nt) acc[nt] = (f32x4){0.f, 0.f, 0.f, 0.f};
    f32x4 accden = (f32x4){0.f, 0.f, 0.f, 0.f};

    // ---- inter: acc += Q * S (B = S^T rows m), den tile nt=4 ----
    #pragma unroll
    for (int nt = 0; nt < 4; ++nt) {
      bf16x8 b0 = *(const bf16x8*)&sSt[li + 16 * nt][8 * lg];
      bf16x8 b1 = *(const bf16x8*)&sSt[li + 16 * nt][32 + 8 * lg];
      acc[nt] = MFMA(aQ0, b0, acc[nt]);
      acc[nt] = MFMA(aQ1, b1, acc[nt]);
    }
    {
      bf16x8 b0 = *(const bf16x8*)&sSt[64 + li][8 * lg];
      bf16x8 b1 = *(const bf16x8*)&sSt[64 + li][32 + 8 * lg];
      accden = MFMA(aQ0, b0, accden);
      accden = MFMA(aQ1, b1, accden);
    }
    float den[4];
    #pragma unroll
    for (int reg = 0; reg < 4; ++reg) den[reg] = __shfl(accden[reg], 16 * lg);

    float rs[4] = {0.f, 0.f, 0.f, 0.f};

    // ---- cross (sub1 only): full attn vs sub0 K, PV with sub0 V ----
    if (s == 1) {
      f32x4 cat[4];
      #pragma unroll
      for (int nt = 0; nt < 4; ++nt) cat[nt] = (f32x4){0.f, 0.f, 0.f, 0.f};
      #pragma unroll
      for (int nt = 0; nt < 4; ++nt) {
        bf16x8 b0 = *(const bf16x8*)&sK[0][li + 16 * nt][8 * lg];
        bf16x8 b1 = *(const bf16x8*)&sK[0][li + 16 * nt][32 + 8 * lg];
        cat[nt] = MFMA(aQ0, b0, cat[nt]);
        cat[nt] = MFMA(aQ1, b1, cat[nt]);
      }
      #pragma unroll
      for (int nt = 0; nt < 4; ++nt) {
        #pragma unroll
        for (int reg = 0; reg < 4; ++reg) {
          float av = cat[nt][reg];
          rs[reg] += av;
          sAt[w][4 * lg + reg][li + 16 * nt] = (__bf16)av;
        }
      }
      bf16x8 aC0 = *(const bf16x8*)&sAt[w][li][8 * lg];
      bf16x8 aC1 = *(const bf16x8*)&sAt[w][li][32 + 8 * lg];
      #pragma unroll
      for (int nt = 0; nt < 4; ++nt) {
        bf16x8 b0 = *(const bf16x8*)&sVt[0][li + 16 * nt][8 * lg];
        bf16x8 b1 = *(const bf16x8*)&sVt[0][li + 16 * nt][32 + 8 * lg];
        acc[nt] = MFMA(aC0, b0, acc[nt]);
        acc[nt] = MFMA(aC1, b1, acc[nt]);
      }
    }

    // ---- intra: masked attn + PV ----
    {
      f32x4 at2[4];
      #pragma unroll
      for (int nt = 0; nt < 4; ++nt) at2[nt] = (f32x4){0.f, 0.f, 0.f, 0.f};
      for (int nt = 0; nt <= w; ++nt) {   // tiles right of the diagonal are fully masked
        bf16x8 b0 = *(const bf16x8*)&sK[s][li + 16 * nt][8 * lg];
        bf16x8 b1 = *(const bf16x8*)&sK[s][li + 16 * nt][32 + 8 * lg];
        at2[nt] = MFMA(aQ0, b0, at2[nt]);
        at2[nt] = MFMA(aQ1, b1, at2[nt]);
      }
      #pragma unroll
      for (int nt = 0; nt < 4; ++nt) {
        #pragma unroll
        for (int reg = 0; reg < 4; ++reg) {
          int row = 16 * w + 4 * lg + reg;
          int col = li + 16 * nt;
          float av = (nt <= w && col <= row) ? at2[nt][reg] : 0.0f;
          rs[reg] += av;
          sAt[w][4 * lg + reg][col] = (__bf16)av;
        }
      }
      bf16x8 aA0 = *(const bf16x8*)&sAt[w][li][8 * lg];
      bf16x8 aA1 = aA0;
      if (w >= 2) aA1 = *(const bf16x8*)&sAt[w][li][32 + 8 * lg];
      #pragma unroll
      for (int nt = 0; nt < 4; ++nt) {
        bf16x8 b0 = *(const bf16x8*)&sVt[s][li + 16 * nt][8 * lg];
        acc[nt] = MFMA(aA0, b0, acc[nt]);
        if (w >= 2) {
          bf16x8 b1 = *(const bf16x8*)&sVt[s][li + 16 * nt][32 + 8 * lg];
          acc[nt] = MFMA(aA1, b1, acc[nt]);
        }
      }
    }

    // ---- reduce rowsums across the 16 cols held per group ----
    #pragma unroll
    for (int reg = 0; reg < 4; ++reg) {
      float v = rs[reg];
      v += __shfl_xor(v, 1);
      v += __shfl_xor(v, 2);
      v += __shfl_xor(v, 4);
      v += __shfl_xor(v, 8);
      rs[reg] = v;
    }

    // ---- normalize + store ----
    #pragma unroll
    for (int reg = 0; reg < 4; ++reg) {
      float inv = 1.0f / (den[reg] + rs[reg] + EPSF);
      int row = l0 + 16 * w + 4 * lg + reg;
      size_t ob = (((size_t)n * LL + row) * HH + h) * EE + li;
      #pragma unroll
      for (int nt = 0; nt < 4; ++nt)
        Og[ob + 16 * nt] = acc[nt][reg] * inv;
    }
    __syncthreads();
  }
}

extern "C" void kernel_launch(void* const* d_in, const int* in_sizes, int n_in,
                              void* d_out, int out_size, void* d_ws, size_t ws_size,
                              hipStream_t stream) {
  const float* Qg  = (const float*)d_in[0];
  const float* Kg  = (const float*)d_in[1];
  const float* Vg  = (const float*)d_in[2];
  const float* KLg = (const float*)d_in[3];
  float* Og = (float*)d_out;

  float* SgT   = (float*)d_ws;                                    // NG * 64*64 floats = 16 MB
  float* KsumG = (float*)((char*)d_ws + (size_t)NG * 4096 * 4);   // NG * 64 floats = 256 KB

  hipLaunchKernelGGL(k_chunksums, dim3(NG), dim3(256), 0, stream, Kg, Vg, KLg, SgT, KsumG);
  hipLaunchKernelGGL(k_prefix, dim3(NN*HH*16), dim3(256), 0, stream, SgT, KsumG);
  hipLaunchKernelGGL(k_pass2, dim3(NG), dim3(256), 0, stream, Qg, Kg, Vg, KLg, SgT, KsumG, Og);
}

// Round 3
// 53.092 us; speedup vs baseline: 2.2229x; 1.3442x over previous
//
#include <hip/hip_runtime.h>
#include <math.h>

#define NN 4
#define LL 4096
#define HH 8
#define EE 64
#define CHK 128
#define SUB 64
#define NCH (LL/CHK)      // 32 chunks per (n,h)
#define NG (NN*HH*NCH)    // 1024 blocks
#define EPSF 1e-6f

typedef float f32x4 __attribute__((ext_vector_type(4)));
typedef __bf16 bf16x8 __attribute__((ext_vector_type(8)));

__device__ __forceinline__ float phi_map(float x) {
  return x > 0.0f ? x + 1.0f : __expf(x);
}

#define MFMA(a, b, c) __builtin_amdgcn_mfma_f32_16x16x32_bf16((a), (b), (c), 0, 0, 0)

// ---- swizzled [64 rows][128 d] bf16 tile: 16B-block XOR along d ----
__device__ __forceinline__ int swz(int row, int d) {
  return row * 128 + (d & 7) + 8 * ((d >> 3) ^ ((row >> 2) & 7));
}
// fragment base covering d = 32*ks + 8*lg .. +7 (16B aligned)
__device__ __forceinline__ int frag_off(int row, int ks, int lg) {
  return row * 128 + 8 * ((4 * ks + lg) ^ ((row >> 2) & 7));
}

// ---------------- Kernel 1: per-(n,h,chunk) S_c^T = V^T K via MFMA; ksum via ones-row
__global__ __launch_bounds__(256) void k_chunksums(
    const float* __restrict__ Kg, const float* __restrict__ Vg,
    const float* __restrict__ KLg, __bf16* __restrict__ ScG, __bf16* __restrict__ KscG)
{
  __shared__ __bf16 sKt[64 * 128];   // K^T [e][d] swizzled
  __shared__ __bf16 sVt[64 * 128];   // V^T [m][d] swizzled
  const int g = blockIdx.x;
  const int c = g % NCH;
  const int nh = g / NCH;
  const int h = nh % HH;
  const int n = nh / HH;
  const int l0 = c * CHK;
  const int t = threadIdx.x;

  #pragma unroll
  for (int it = 0; it < 8; ++it) {
    int f = t + 256 * it;
    int d = f >> 4;                 // 0..127
    int c4 = (f & 15) << 2;         // e base
    size_t gb = (((size_t)n * LL + (size_t)(l0 + d)) * HH + h) * EE + c4;
    float4 kk = *(const float4*)(Kg + gb);
    float4 vv = *(const float4*)(Vg + gb);
    float klr = KLg[n * LL + l0 + d];
    float ka[4] = {phi_map(kk.x) * klr, phi_map(kk.y) * klr,
                   phi_map(kk.z) * klr, phi_map(kk.w) * klr};
    float va[4] = {vv.x, vv.y, vv.z, vv.w};
    #pragma unroll
    for (int j = 0; j < 4; ++j) {
      sKt[swz(c4 + j, d)] = (__bf16)ka[j];
      sVt[swz(c4 + j, d)] = (__bf16)va[j];
    }
  }
  __syncthreads();

  const int w = t >> 6;
  const int lane = t & 63;
  const int lg = lane >> 4;
  const int li = lane & 15;

  bf16x8 aV[4];
  #pragma unroll
  for (int ks = 0; ks < 4; ++ks)
    aV[ks] = *(const bf16x8*)&sVt[frag_off(16 * w + li, ks, lg)];

  bf16x8 ones;
  #pragma unroll
  for (int i = 0; i < 8; ++i) ones[i] = (__bf16)1.0f;

  f32x4 acc[4], accK[4];
  #pragma unroll
  for (int nt = 0; nt < 4; ++nt) {
    acc[nt] = (f32x4){0.f, 0.f, 0.f, 0.f};
    accK[nt] = (f32x4){0.f, 0.f, 0.f, 0.f};
  }

  #pragma unroll
  for (int nt = 0; nt < 4; ++nt) {
    #pragma unroll
    for (int ks = 0; ks < 4; ++ks) {
      bf16x8 b = *(const bf16x8*)&sKt[frag_off(li + 16 * nt, ks, lg)];
      acc[nt] = MFMA(aV[ks], b, acc[nt]);
      if (w == 0) accK[nt] = MFMA(ones, b, accK[nt]);
    }
  }

  __bf16* sp = ScG + (size_t)g * 4096;
  #pragma unroll
  for (int nt = 0; nt < 4; ++nt)
    #pragma unroll
    for (int reg = 0; reg < 4; ++reg)
      sp[(16 * w + 4 * lg + reg) * 64 + li + 16 * nt] = (__bf16)acc[nt][reg];

  if (w == 0 && lg == 0) {
    #pragma unroll
    for (int nt = 0; nt < 4; ++nt)
      KscG[(size_t)g * 64 + li + 16 * nt] = (__bf16)accK[nt][0];
  }
}

// ---------------- Kernel 2: exclusive prefix over the 32 chunks of each (n,h)
__global__ __launch_bounds__(256) void k_prefix(
    const __bf16* __restrict__ Sc, __bf16* __restrict__ Sp,
    const __bf16* __restrict__ Ksc, __bf16* __restrict__ Ksp)
{
  const int bid = blockIdx.x;       // nh*16 + strip
  const int nh = bid >> 4;
  const int strip = bid & 15;
  const int t = threadIdx.x;
  const int entry = strip * 256 + t;
  float run = 0.0f;
  for (int c = 0; c < NCH; ++c) {
    size_t base = ((size_t)nh * NCH + c) * 4096 + entry;
    float v = (float)Sc[base];
    Sp[base] = (__bf16)run;
    run += v;
  }
  if (strip == 0 && t < 64) {
    float kr = 0.0f;
    for (int c = 0; c < NCH; ++c) {
      size_t kb = ((size_t)nh * NCH + c) * 64 + t;
      float v = (float)Ksc[kb];
      Ksp[kb] = (__bf16)kr;
      kr += v;
    }
  }
}

// ---------------- Kernel 3: per-chunk output via bf16 MFMA (two 64-row sub-chunks)
__global__ __launch_bounds__(256) void k_pass2(
    const float* __restrict__ Qg, const float* __restrict__ Kg,
    const float* __restrict__ Vg, const float* __restrict__ KLg,
    const __bf16* __restrict__ Sp, const __bf16* __restrict__ Ksp,
    float* __restrict__ Og)
{
  __shared__ __bf16 sK[2][64][72];     // phi(K)*kl row-major [row][e], per sub
  __shared__ __bf16 sVt[2][64][72];    // V transposed [m][d], per sub
  __shared__ __bf16 sSt[80][72];       // S^T [m][e]; row 64 = ksum_prefix; rows 65-79 zero
  __shared__ __bf16 sAt[4][16][72];    // per-wave attn rows [qrow][d]

  const int g = blockIdx.x;
  const int c = g % NCH;
  const int nh = g / NCH;
  const int h = nh % HH;
  const int n = nh / HH;
  const int t = threadIdx.x;
  const int w = t >> 6;
  const int lane = t & 63;
  const int lg = lane >> 4;
  const int li = lane & 15;

  // ---- load S^T prefix (bf16, vectorized) ----
  {
    const bf16x8* sp8 = (const bf16x8*)(Sp + (size_t)g * 4096);
    bf16x8 s0 = sp8[2 * t];
    bf16x8 s1 = sp8[2 * t + 1];
    int m = t >> 2;
    int e0 = (t & 3) * 16;
    *(bf16x8*)&sSt[m][e0] = s0;
    *(bf16x8*)&sSt[m][e0 + 8] = s1;
    if (t < 64) sSt[64][t] = Ksp[(size_t)g * 64 + t];
    for (int i = t; i < 15 * 72; i += 256) sSt[65 + i / 72][i % 72] = (__bf16)0.0f;
  }

  for (int s = 0; s < 2; ++s) {
    const int l0 = c * CHK + s * SUB;
    const int arow = 16 * w + li;

    // ---- Q fragments straight from global (e contiguous) ----
    const float* qrow = Qg + (((size_t)n * LL + (size_t)(l0 + arow)) * HH + h) * EE;
    float4 q0 = *(const float4*)(qrow + 8 * lg);
    float4 q1 = *(const float4*)(qrow + 8 * lg + 4);
    float4 q2 = *(const float4*)(qrow + 32 + 8 * lg);
    float4 q3 = *(const float4*)(qrow + 32 + 8 * lg + 4);

    // ---- stage phi(K)*kl and V^T for this sub ----
    #pragma unroll
    for (int it = 0; it < 4; ++it) {
      int f = t + 256 * it;
      int rr = f >> 4;
      int c4 = (f & 15) << 2;
      size_t gb = (((size_t)n * LL + (size_t)(l0 + rr)) * HH + h) * EE + c4;
      float4 kk = *(const float4*)(Kg + gb);
      float4 vv = *(const float4*)(Vg + gb);
      float klr = KLg[n * LL + l0 + rr];
      __bf16* kd = &sK[s][rr][c4];
      kd[0] = (__bf16)(phi_map(kk.x) * klr); kd[1] = (__bf16)(phi_map(kk.y) * klr);
      kd[2] = (__bf16)(phi_map(kk.z) * klr); kd[3] = (__bf16)(phi_map(kk.w) * klr);
      sVt[s][c4 + 0][rr] = (__bf16)vv.x;
      sVt[s][c4 + 1][rr] = (__bf16)vv.y;
      sVt[s][c4 + 2][rr] = (__bf16)vv.z;
      sVt[s][c4 + 3][rr] = (__bf16)vv.w;
    }

    bf16x8 aQ0, aQ1;
    aQ0[0] = (__bf16)phi_map(q0.x); aQ0[1] = (__bf16)phi_map(q0.y);
    aQ0[2] = (__bf16)phi_map(q0.z); aQ0[3] = (__bf16)phi_map(q0.w);
    aQ0[4] = (__bf16)phi_map(q1.x); aQ0[5] = (__bf16)phi_map(q1.y);
    aQ0[6] = (__bf16)phi_map(q1.z); aQ0[7] = (__bf16)phi_map(q1.w);
    aQ1[0] = (__bf16)phi_map(q2.x); aQ1[1] = (__bf16)phi_map(q2.y);
    aQ1[2] = (__bf16)phi_map(q2.z); aQ1[3] = (__bf16)phi_map(q2.w);
    aQ1[4] = (__bf16)phi_map(q3.x); aQ1[5] = (__bf16)phi_map(q3.y);
    aQ1[6] = (__bf16)phi_map(q3.z); aQ1[7] = (__bf16)phi_map(q3.w);

    __syncthreads();

    f32x4 acc[4];
    #pragma unroll
    for (int nt = 0; nt < 4; ++nt) acc[nt] = (f32x4){0.f, 0.f, 0.f, 0.f};
    f32x4 accden = (f32x4){0.f, 0.f, 0.f, 0.f};

    // ---- inter: acc += Q * S (B = S^T rows m), den tile ----
    #pragma unroll
    for (int nt = 0; nt < 4; ++nt) {
      bf16x8 b0 = *(const bf16x8*)&sSt[li + 16 * nt][8 * lg];
      bf16x8 b1 = *(const bf16x8*)&sSt[li + 16 * nt][32 + 8 * lg];
      acc[nt] = MFMA(aQ0, b0, acc[nt]);
      acc[nt] = MFMA(aQ1, b1, acc[nt]);
    }
    {
      bf16x8 b0 = *(const bf16x8*)&sSt[64 + li][8 * lg];
      bf16x8 b1 = *(const bf16x8*)&sSt[64 + li][32 + 8 * lg];
      accden = MFMA(aQ0, b0, accden);
      accden = MFMA(aQ1, b1, accden);
    }
    float den[4];
    #pragma unroll
    for (int reg = 0; reg < 4; ++reg) den[reg] = __shfl(accden[reg], 16 * lg);

    float rs[4] = {0.f, 0.f, 0.f, 0.f};

    // ---- cross (sub1 only): full attn vs sub0 K, PV with sub0 V ----
    if (s == 1) {
      f32x4 cat[4];
      #pragma unroll
      for (int nt = 0; nt < 4; ++nt) cat[nt] = (f32x4){0.f, 0.f, 0.f, 0.f};
      #pragma unroll
      for (int nt = 0; nt < 4; ++nt) {
        bf16x8 b0 = *(const bf16x8*)&sK[0][li + 16 * nt][8 * lg];
        bf16x8 b1 = *(const bf16x8*)&sK[0][li + 16 * nt][32 + 8 * lg];
        cat[nt] = MFMA(aQ0, b0, cat[nt]);
        cat[nt] = MFMA(aQ1, b1, cat[nt]);
      }
      #pragma unroll
      for (int nt = 0; nt < 4; ++nt) {
        #pragma unroll
        for (int reg = 0; reg < 4; ++reg) {
          float av = cat[nt][reg];
          rs[reg] += av;
          sAt[w][4 * lg + reg][li + 16 * nt] = (__bf16)av;
        }
      }
      bf16x8 aC0 = *(const bf16x8*)&sAt[w][li][8 * lg];
      bf16x8 aC1 = *(const bf16x8*)&sAt[w][li][32 + 8 * lg];
      #pragma unroll
      for (int nt = 0; nt < 4; ++nt) {
        bf16x8 b0 = *(const bf16x8*)&sVt[0][li + 16 * nt][8 * lg];
        bf16x8 b1 = *(const bf16x8*)&sVt[0][li + 16 * nt][32 + 8 * lg];
        acc[nt] = MFMA(aC0, b0, acc[nt]);
        acc[nt] = MFMA(aC1, b1, acc[nt]);
      }
    }

    // ---- intra: masked attn + PV ----
    {
      f32x4 at2[4];
      #pragma unroll
      for (int nt = 0; nt < 4; ++nt) at2[nt] = (f32x4){0.f, 0.f, 0.f, 0.f};
      for (int nt = 0; nt <= w; ++nt) {
        bf16x8 b0 = *(const bf16x8*)&sK[s][li + 16 * nt][8 * lg];
        bf16x8 b1 = *(const bf16x8*)&sK[s][li + 16 * nt][32 + 8 * lg];
        at2[nt] = MFMA(aQ0, b0, at2[nt]);
        at2[nt] = MFMA(aQ1, b1, at2[nt]);
      }
      #pragma unroll
      for (int nt = 0; nt < 4; ++nt) {
        #pragma unroll
        for (int reg = 0; reg < 4; ++reg) {
          int row = 16 * w + 4 * lg + reg;
          int col = li + 16 * nt;
          float av = (nt <= w && col <= row) ? at2[nt][reg] : 0.0f;
          rs[reg] += av;
          sAt[w][4 * lg + reg][col] = (__bf16)av;
        }
      }
      bf16x8 aA0 = *(const bf16x8*)&sAt[w][li][8 * lg];
      bf16x8 aA1 = aA0;
      if (w >= 2) aA1 = *(const bf16x8*)&sAt[w][li][32 + 8 * lg];
      #pragma unroll
      for (int nt = 0; nt < 4; ++nt) {
        bf16x8 b0 = *(const bf16x8*)&sVt[s][li + 16 * nt][8 * lg];
        acc[nt] = MFMA(aA0, b0, acc[nt]);
        if (w >= 2) {
          bf16x8 b1 = *(const bf16x8*)&sVt[s][li + 16 * nt][32 + 8 * lg];
          acc[nt] = MFMA(aA1, b1, acc[nt]);
        }
      }
    }

    // ---- reduce rowsums across the 16 cols held per group ----
    #pragma unroll
    for (int reg = 0; reg < 4; ++reg) {
      float v = rs[reg];
      v += __shfl_xor(v, 1);
      v += __shfl_xor(v, 2);
      v += __shfl_xor(v, 4);
      v += __shfl_xor(v, 8);
      rs[reg] = v;
    }

    // ---- normalize + store ----
    #pragma unroll
    for (int reg = 0; reg < 4; ++reg) {
      float inv = 1.0f / (den[reg] + rs[reg] + EPSF);
      int row = l0 + 16 * w + 4 * lg + reg;
      size_t ob = (((size_t)n * LL + row) * HH + h) * EE + li;
      #pragma unroll
      for (int nt = 0; nt < 4; ++nt)
        Og[ob + 16 * nt] = acc[nt][reg] * inv;
    }
    __syncthreads();
  }
}

extern "C" void kernel_launch(void* const* d_in, const int* in_sizes, int n_in,
                              void* d_out, int out_size, void* d_ws, size_t ws_size,
                              hipStream_t stream) {
  const float* Qg  = (const float*)d_in[0];
  const float* Kg  = (const float*)d_in[1];
  const float* Vg  = (const float*)d_in[2];
  const float* KLg = (const float*)d_in[3];
  float* Og = (float*)d_out;

  // ws: Sc bf16 8MB | Sp bf16 8MB | Ksc bf16 128KB | Ksp bf16 128KB  (= 16.25 MB)
  __bf16* Sc  = (__bf16*)d_ws;
  __bf16* Sp  = (__bf16*)((char*)d_ws + (size_t)NG * 4096 * 2);
  __bf16* Ksc = (__bf16*)((char*)d_ws + (size_t)NG * 4096 * 4);
  __bf16* Ksp = (__bf16*)((char*)d_ws + (size_t)NG * 4096 * 4 + (size_t)NG * 64 * 2);

  hipLaunchKernelGGL(k_chunksums, dim3(NG), dim3(256), 0, stream, Kg, Vg, KLg, Sc, Ksc);
  hipLaunchKernelGGL(k_prefix, dim3(NN*HH*16), dim3(256), 0, stream, Sc, Sp, Ksc, Ksp);
  hipLaunchKernelGGL(k_pass2, dim3(NG), dim3(256), 0, stream, Qg, Kg, Vg, KLg, Sp, Ksp, Og);
}

// Round 4
// 51.343 us; speedup vs baseline: 2.2986x; 1.0340x over previous
//
#include <hip/hip_runtime.h>
#include <math.h>

#define NN 4
#define LL 4096
#define HH 8
#define EE 64
#define CHK 64
#define NCH (LL/CHK)      // 64 chunks per (n,h)
#define NG (NN*HH*NCH)    // 2048 blocks
#define EPSF 1e-6f

typedef float f32x4 __attribute__((ext_vector_type(4)));
typedef __bf16 bf16x8 __attribute__((ext_vector_type(8)));

__device__ __forceinline__ float phi_map(float x) {
  return x > 0.0f ? x + 1.0f : __expf(x);
}

#define MFMA(a, b, c) __builtin_amdgcn_mfma_f32_16x16x32_bf16((a), (b), (c), 0, 0, 0)

// ---- swizzled [64 rows][64 d] bf16 tile: 16B-block XOR along d (k1-proven, 0 conflicts) ----
__device__ __forceinline__ int swz64(int row, int d) {
  return row * 64 + (d & 7) + 8 * ((d >> 3) ^ ((row >> 2) & 7));
}
// fragment base covering d-block blk (8 bf16, 16B aligned)
__device__ __forceinline__ int frag64(int row, int blk) {
  return row * 64 + 8 * (blk ^ ((row >> 2) & 7));
}

// ---------------- Kernel 1: per-(n,h,chunk64) S_c^T = V^T K via MFMA; ksum via ones-row
__global__ __launch_bounds__(256) void k_chunksums(
    const float* __restrict__ Kg, const float* __restrict__ Vg,
    const float* __restrict__ KLg, __bf16* __restrict__ ScG, __bf16* __restrict__ KscG)
{
  __shared__ __bf16 sKt[4096];   // K^T [e][d] swizzled
  __shared__ __bf16 sVt[4096];   // V^T [m][d] swizzled
  const int g = blockIdx.x;
  const int c = g % NCH;
  const int nh = g / NCH;
  const int h = nh % HH;
  const int n = nh / HH;
  const int l0 = c * CHK;
  const int t = threadIdx.x;

  #pragma unroll
  for (int it = 0; it < 4; ++it) {
    int f = t + 256 * it;           // float4 unit 0..1023
    int d = f >> 4;                 // chunk row 0..63
    int c4 = (f & 15) << 2;         // feature base
    size_t gb = (((size_t)n * LL + (size_t)(l0 + d)) * HH + h) * EE + c4;
    float4 kk = *(const float4*)(Kg + gb);
    float4 vv = *(const float4*)(Vg + gb);
    float klr = KLg[n * LL + l0 + d];
    float ka[4] = {phi_map(kk.x) * klr, phi_map(kk.y) * klr,
                   phi_map(kk.z) * klr, phi_map(kk.w) * klr};
    float va[4] = {vv.x, vv.y, vv.z, vv.w};
    #pragma unroll
    for (int j = 0; j < 4; ++j) {
      sKt[swz64(c4 + j, d)] = (__bf16)ka[j];
      sVt[swz64(c4 + j, d)] = (__bf16)va[j];
    }
  }
  __syncthreads();

  const int w = t >> 6;
  const int lane = t & 63;
  const int lg = lane >> 4;
  const int li = lane & 15;

  bf16x8 aV[2];
  #pragma unroll
  for (int ks = 0; ks < 2; ++ks)
    aV[ks] = *(const bf16x8*)&sVt[frag64(16 * w + li, 4 * ks + lg)];

  bf16x8 ones;
  #pragma unroll
  for (int i = 0; i < 8; ++i) ones[i] = (__bf16)1.0f;

  f32x4 acc[4], accK[4];
  #pragma unroll
  for (int nt = 0; nt < 4; ++nt) {
    acc[nt] = (f32x4){0.f, 0.f, 0.f, 0.f};
    accK[nt] = (f32x4){0.f, 0.f, 0.f, 0.f};
  }

  #pragma unroll
  for (int nt = 0; nt < 4; ++nt) {
    #pragma unroll
    for (int ks = 0; ks < 2; ++ks) {
      bf16x8 b = *(const bf16x8*)&sKt[frag64(li + 16 * nt, 4 * ks + lg)];
      acc[nt] = MFMA(aV[ks], b, acc[nt]);
      if (w == 0) accK[nt] = MFMA(ones, b, accK[nt]);
    }
  }

  __bf16* sp = ScG + (size_t)g * 4096;
  #pragma unroll
  for (int nt = 0; nt < 4; ++nt)
    #pragma unroll
    for (int reg = 0; reg < 4; ++reg)
      sp[(16 * w + 4 * lg + reg) * 64 + li + 16 * nt] = (__bf16)acc[nt][reg];

  if (w == 0 && lg == 0) {
    #pragma unroll
    for (int nt = 0; nt < 4; ++nt)
      KscG[(size_t)g * 64 + li + 16 * nt] = (__bf16)accK[nt][0];
  }
}

// ---------------- Kernel 2: exclusive prefix over 64 chunks, in place, two-phase
__global__ __launch_bounds__(256) void k_prefix(
    __bf16* __restrict__ Sc, __bf16* __restrict__ Ksc)
{
  const int bid = blockIdx.x;
  const int t = threadIdx.x;
  if (bid < NN * HH * 16) {
    const int nh = bid >> 4;
    const int strip = bid & 15;
    const int entry = strip * 256 + t;          // 0..4095
    __bf16 v[NCH];
    #pragma unroll
    for (int c = 0; c < NCH; ++c)
      v[c] = Sc[((size_t)(nh * NCH + c) << 12) + entry];
    float run = 0.0f;
    #pragma unroll
    for (int c = 0; c < NCH; ++c) {
      Sc[((size_t)(nh * NCH + c) << 12) + entry] = (__bf16)run;
      run += (float)v[c];
    }
  } else {
    const int idx = (bid - NN * HH * 16) * 256 + t;   // 0..2047
    const int nh = idx >> 6;
    const int e = idx & 63;
    __bf16 v[NCH];
    #pragma unroll
    for (int c = 0; c < NCH; ++c)
      v[c] = Ksc[((size_t)(nh * NCH + c) << 6) + e];
    float run = 0.0f;
    #pragma unroll
    for (int c = 0; c < NCH; ++c) {
      Ksc[((size_t)(nh * NCH + c) << 6) + e] = (__bf16)run;
      run += (float)v[c];
    }
  }
}

// ---------------- Kernel 3: per-64-chunk output via bf16 MFMA
__global__ __launch_bounds__(256, 6) void k_pass2(
    const float* __restrict__ Qg, const float* __restrict__ Kg,
    const float* __restrict__ Vg, const float* __restrict__ KLg,
    const __bf16* __restrict__ Sp, const __bf16* __restrict__ Ksp,
    float* __restrict__ Og)
{
  __shared__ __bf16 sK[64][72];   // phi(K)*kl row-major [d][e]
  __shared__ __bf16 sVt[4096];    // V^T [m][d] swizzled
  __shared__ __bf16 sU[4608];     // sSt [m][e] (64x72) ... then sAt [w][16][72] overlay

  const int g = blockIdx.x;
  const int c = g % NCH;
  const int nh = g / NCH;
  const int h = nh % HH;
  const int n = nh / HH;
  const int t = threadIdx.x;
  const int w = t >> 6;
  const int lane = t & 63;
  const int lg = lane >> 4;
  const int li = lane & 15;
  const int l0 = c * CHK;

  // ---- stage S^T prefix into sU (as sSt[m][e], stride 72) ----
  {
    const bf16x8* sp8 = (const bf16x8*)(Sp + (size_t)g * 4096);
    bf16x8 s0 = sp8[2 * t];
    bf16x8 s1 = sp8[2 * t + 1];
    int m = t >> 2;
    int e0 = (t & 3) * 16;
    *(bf16x8*)&sU[m * 72 + e0] = s0;
    *(bf16x8*)&sU[m * 72 + e0 + 8] = s1;
  }

  // ---- stage phi(K)*kl row-major, V^T swizzled ----
  #pragma unroll
  for (int it = 0; it < 4; ++it) {
    int f = t + 256 * it;
    int rr = f >> 4;                // row d
    int c4 = (f & 15) << 2;
    size_t gb = (((size_t)n * LL + (size_t)(l0 + rr)) * HH + h) * EE + c4;
    float4 kk = *(const float4*)(Kg + gb);
    float4 vv = *(const float4*)(Vg + gb);
    float klr = KLg[n * LL + l0 + rr];
    __bf16* kd = &sK[rr][c4];
    kd[0] = (__bf16)(phi_map(kk.x) * klr); kd[1] = (__bf16)(phi_map(kk.y) * klr);
    kd[2] = (__bf16)(phi_map(kk.z) * klr); kd[3] = (__bf16)(phi_map(kk.w) * klr);
    float va[4] = {vv.x, vv.y, vv.z, vv.w};
    #pragma unroll
    for (int j = 0; j < 4; ++j)
      sVt[swz64(c4 + j, rr)] = (__bf16)va[j];
  }

  // ---- Q fragments straight from global + phi ----
  const int arow = 16 * w + li;
  const float* qrow = Qg + (((size_t)n * LL + (size_t)(l0 + arow)) * HH + h) * EE;
  float4 q0 = *(const float4*)(qrow + 8 * lg);
  float4 q1 = *(const float4*)(qrow + 8 * lg + 4);
  float4 q2 = *(const float4*)(qrow + 32 + 8 * lg);
  float4 q3 = *(const float4*)(qrow + 32 + 8 * lg + 4);
  bf16x8 aQ0, aQ1;
  aQ0[0] = (__bf16)phi_map(q0.x); aQ0[1] = (__bf16)phi_map(q0.y);
  aQ0[2] = (__bf16)phi_map(q0.z); aQ0[3] = (__bf16)phi_map(q0.w);
  aQ0[4] = (__bf16)phi_map(q1.x); aQ0[5] = (__bf16)phi_map(q1.y);
  aQ0[6] = (__bf16)phi_map(q1.z); aQ0[7] = (__bf16)phi_map(q1.w);
  aQ1[0] = (__bf16)phi_map(q2.x); aQ1[1] = (__bf16)phi_map(q2.y);
  aQ1[2] = (__bf16)phi_map(q2.z); aQ1[3] = (__bf16)phi_map(q2.w);
  aQ1[4] = (__bf16)phi_map(q3.x); aQ1[5] = (__bf16)phi_map(q3.y);
  aQ1[6] = (__bf16)phi_map(q3.z); aQ1[7] = (__bf16)phi_map(q3.w);

  // ---- ksum_prefix slices for the VALU denominator ----
  const __bf16* kb = Ksp + (size_t)g * 64;
  bf16x8 ks0 = *(const bf16x8*)(kb + 8 * lg);
  bf16x8 ks1 = *(const bf16x8*)(kb + 32 + 8 * lg);

  __syncthreads();

  // ---- inter: acc += Q * S (B = S^T rows m) ----
  f32x4 acc[4];
  #pragma unroll
  for (int nt = 0; nt < 4; ++nt) acc[nt] = (f32x4){0.f, 0.f, 0.f, 0.f};
  #pragma unroll
  for (int nt = 0; nt < 4; ++nt) {
    bf16x8 b0 = *(const bf16x8*)&sU[(li + 16 * nt) * 72 + 8 * lg];
    bf16x8 b1 = *(const bf16x8*)&sU[(li + 16 * nt) * 72 + 32 + 8 * lg];
    acc[nt] = MFMA(aQ0, b0, acc[nt]);
    acc[nt] = MFMA(aQ1, b1, acc[nt]);
  }

  // ---- den = q . ksum_prefix (VALU + shfl) ----
  float dv = 0.0f;
  #pragma unroll
  for (int i = 0; i < 8; ++i) {
    dv += (float)aQ0[i] * (float)ks0[i];
    dv += (float)aQ1[i] * (float)ks1[i];
  }
  dv += __shfl_xor(dv, 16);
  dv += __shfl_xor(dv, 32);              // all lanes: den for row 16w+li
  float den[4];
  #pragma unroll
  for (int reg = 0; reg < 4; ++reg) den[reg] = __shfl(dv, 4 * lg + reg);

  __syncthreads();   // all waves done reading sSt -> sAt may overlay sU

  // ---- intra: masked attn (per n-tile, fused mask+write) ----
  float rs[4] = {0.f, 0.f, 0.f, 0.f};
  #pragma unroll
  for (int nt = 0; nt < 4; ++nt) {
    f32x4 at2 = (f32x4){0.f, 0.f, 0.f, 0.f};
    if (nt <= w) {
      bf16x8 b0 = *(const bf16x8*)&sK[li + 16 * nt][8 * lg];
      bf16x8 b1 = *(const bf16x8*)&sK[li + 16 * nt][32 + 8 * lg];
      at2 = MFMA(aQ0, b0, at2);
      at2 = MFMA(aQ1, b1, at2);
    }
    #pragma unroll
    for (int reg = 0; reg < 4; ++reg) {
      int row = 16 * w + 4 * lg + reg;
      int col = li + 16 * nt;
      float av = (col <= row) ? at2[reg] : 0.0f;
      rs[reg] += av;
      sU[w * 1152 + (4 * lg + reg) * 72 + col] = (__bf16)av;
    }
  }

  // ---- PV: acc += P * V ----
  {
    bf16x8 aA0 = *(const bf16x8*)&sU[w * 1152 + li * 72 + 8 * lg];
    bf16x8 aA1 = aA0;
    if (w >= 2) aA1 = *(const bf16x8*)&sU[w * 1152 + li * 72 + 32 + 8 * lg];
    #pragma unroll
    for (int nt = 0; nt < 4; ++nt) {
      bf16x8 bv0 = *(const bf16x8*)&sVt[frag64(li + 16 * nt, lg)];
      acc[nt] = MFMA(aA0, bv0, acc[nt]);
      if (w >= 2) {
        bf16x8 bv1 = *(const bf16x8*)&sVt[frag64(li + 16 * nt, 4 + lg)];
        acc[nt] = MFMA(aA1, bv1, acc[nt]);
      }
    }
  }

  // ---- reduce rowsums across the 16 cols held per group ----
  #pragma unroll
  for (int reg = 0; reg < 4; ++reg) {
    float v = rs[reg];
    v += __shfl_xor(v, 1);
    v += __shfl_xor(v, 2);
    v += __shfl_xor(v, 4);
    v += __shfl_xor(v, 8);
    rs[reg] = v;
  }

  // ---- normalize + store ----
  #pragma unroll
  for (int reg = 0; reg < 4; ++reg) {
    float inv = 1.0f / (den[reg] + rs[reg] + EPSF);
    int row = l0 + 16 * w + 4 * lg + reg;
    size_t ob = (((size_t)n * LL + row) * HH + h) * EE + li;
    #pragma unroll
    for (int nt = 0; nt < 4; ++nt)
      Og[ob + 16 * nt] = acc[nt][reg] * inv;
  }
}

extern "C" void kernel_launch(void* const* d_in, const int* in_sizes, int n_in,
                              void* d_out, int out_size, void* d_ws, size_t ws_size,
                              hipStream_t stream) {
  const float* Qg  = (const float*)d_in[0];
  const float* Kg  = (const float*)d_in[1];
  const float* Vg  = (const float*)d_in[2];
  const float* KLg = (const float*)d_in[3];
  float* Og = (float*)d_out;

  // ws: Sc bf16 16MB | Ksc bf16 256KB (prefix done in place)
  __bf16* Sc  = (__bf16*)d_ws;
  __bf16* Ksc = (__bf16*)((char*)d_ws + (size_t)NG * 4096 * 2);

  hipLaunchKernelGGL(k_chunksums, dim3(NG), dim3(256), 0, stream, Kg, Vg, KLg, Sc, Ksc);
  hipLaunchKernelGGL(k_prefix, dim3(NN*HH*16 + 8), dim3(256), 0, stream, Sc, Ksc);
  hipLaunchKernelGGL(k_pass2, dim3(NG), dim3(256), 0, stream, Qg, Kg, Vg, KLg, Sc, Ksc, Og);
}

// Round 5
// 48.096 us; speedup vs baseline: 2.4538x; 1.0675x over previous
//
#include <hip/hip_runtime.h>
#include <math.h>

#define NN 4
#define LL 4096
#define HH 8
#define EE 64
#define CHK 64            // compute chunk rows
#define GSUP 4            // chunks per super-chunk
#define SUPC (CHK*GSUP)   // 256 rows
#define NSUP (LL/SUPC)    // 16 supers per (n,h)
#define NH (NN*HH)        // 32
#define NBLK (NH*NSUP)    // 512 blocks
#define NCH64 (LL/CHK)    // 64 chunks per (n,h)
#define EPSF 1e-6f

typedef float f32x4 __attribute__((ext_vector_type(4)));
typedef __bf16 bf16x8 __attribute__((ext_vector_type(8)));

__device__ __forceinline__ float phi_map(float x) {
  return x > 0.0f ? x + 1.0f : __expf(x);
}

#define MFMA(a, b, c) __builtin_amdgcn_mfma_f32_16x16x32_bf16((a), (b), (c), 0, 0, 0)

// ---- swizzled [64 rows][64 d] bf16 tile: 16B-block XOR along d (proven 0-conflict) ----
__device__ __forceinline__ int swz64(int row, int d) {
  return row * 64 + (d & 7) + 8 * ((d >> 3) ^ ((row >> 2) & 7));
}
__device__ __forceinline__ int frag64(int row, int blk) {
  return row * 64 + 8 * (blk ^ ((row >> 2) & 7));
}

// ================= Kernel 1: per-super-chunk S^T = sum_4tiles V^T K; per-64-chunk ksum =================
#define K1_ISSUE(J, BUF) { \
  const int l0i = (sc * GSUP + (J)) * CHK; \
  _Pragma("unroll") for (int it = 0; it < 4; ++it) { \
    int f = t + 256 * it; int d = f >> 4; int c4 = (f & 15) << 2; \
    size_t gb = (((size_t)n * LL + (size_t)(l0i + d)) * HH + h) * EE + c4; \
    pk[BUF][it] = *(const float4*)(Kg + gb); \
    pv[BUF][it] = *(const float4*)(Vg + gb); \
    pl[BUF][it] = KLg[n * LL + l0i + d]; } }

#define K1_STAGE(BUF) { \
  _Pragma("unroll") for (int it = 0; it < 4; ++it) { \
    int f = t + 256 * it; int d = f >> 4; int c4 = (f & 15) << 2; \
    float klr = pl[BUF][it]; float4 kk = pk[BUF][it]; float4 vv = pv[BUF][it]; \
    float ka[4] = {phi_map(kk.x) * klr, phi_map(kk.y) * klr, phi_map(kk.z) * klr, phi_map(kk.w) * klr}; \
    float va[4] = {vv.x, vv.y, vv.z, vv.w}; \
    _Pragma("unroll") for (int jj = 0; jj < 4; ++jj) { \
      sKt[BUF][swz64(c4 + jj, d)] = (__bf16)ka[jj]; \
      sVt[BUF][swz64(c4 + jj, d)] = (__bf16)va[jj]; } } }

__global__ __launch_bounds__(256, 2) void k_chunksums(
    const float* __restrict__ Kg, const float* __restrict__ Vg,
    const float* __restrict__ KLg, __bf16* __restrict__ ScG, __bf16* __restrict__ KscG)
{
  __shared__ __bf16 sKt[2][4096];
  __shared__ __bf16 sVt[2][4096];
  const int g = blockIdx.x;        // nh*NSUP + sc
  const int sc = g % NSUP;
  const int nh = g / NSUP;
  const int h = nh % HH;
  const int n = nh / HH;
  const int t = threadIdx.x;
  const int w = t >> 6;
  const int lane = t & 63;
  const int lg = lane >> 4;
  const int li = lane & 15;

  float4 pk[2][4], pv[2][4];
  float pl[2][4];

  K1_ISSUE(0, 0);
  K1_STAGE(0);

  f32x4 acc[4];
  #pragma unroll
  for (int nt = 0; nt < 4; ++nt) acc[nt] = (f32x4){0.f, 0.f, 0.f, 0.f};

  bf16x8 ones;
  #pragma unroll
  for (int i = 0; i < 8; ++i) ones[i] = (__bf16)1.0f;

  #pragma unroll
  for (int j = 0; j < GSUP; ++j) {
    if (j + 1 < GSUP) K1_ISSUE(j + 1, (j + 1) & 1);
    __syncthreads();   // staged buf j visible; buf (j+1)&1 readers (iter j-1) done

    bf16x8 aV0 = *(const bf16x8*)&sVt[j & 1][frag64(16 * w + li, lg)];
    bf16x8 aV1 = *(const bf16x8*)&sVt[j & 1][frag64(16 * w + li, 4 + lg)];

    f32x4 accK[4];
    #pragma unroll
    for (int nt = 0; nt < 4; ++nt) accK[nt] = (f32x4){0.f, 0.f, 0.f, 0.f};

    #pragma unroll
    for (int nt = 0; nt < 4; ++nt) {
      bf16x8 b0 = *(const bf16x8*)&sKt[j & 1][frag64(li + 16 * nt, lg)];
      bf16x8 b1 = *(const bf16x8*)&sKt[j & 1][frag64(li + 16 * nt, 4 + lg)];
      acc[nt] = MFMA(aV0, b0, acc[nt]);
      acc[nt] = MFMA(aV1, b1, acc[nt]);
      if (w == 0) {
        accK[nt] = MFMA(ones, b0, accK[nt]);
        accK[nt] = MFMA(ones, b1, accK[nt]);
      }
    }
    if (w == 0 && lg == 0) {
      #pragma unroll
      for (int nt = 0; nt < 4; ++nt)
        KscG[(size_t)(g * GSUP + j) * 64 + li + 16 * nt] = (__bf16)accK[nt][0];
    }
    if (j + 1 < GSUP) K1_STAGE((j + 1) & 1);
  }

  __bf16* sp = ScG + (size_t)g * 4096;
  #pragma unroll
  for (int nt = 0; nt < 4; ++nt)
    #pragma unroll
    for (int reg = 0; reg < 4; ++reg)
      sp[(16 * w + 4 * lg + reg) * 64 + li + 16 * nt] = (__bf16)acc[nt][reg];
}

// ================= Kernel 2: exclusive prefixes (S at super granularity, ksum at 64 granularity) =================
__global__ __launch_bounds__(256) void k_prefix(
    __bf16* __restrict__ Sc, __bf16* __restrict__ Ksc)
{
  const int bid = blockIdx.x;
  const int t = threadIdx.x;
  if (bid < NH * 16) {
    const int nh = bid >> 4;
    const int strip = bid & 15;
    const int entry = strip * 256 + t;          // 0..4095
    __bf16 v[NSUP];
    #pragma unroll
    for (int c = 0; c < NSUP; ++c)
      v[c] = Sc[((size_t)(nh * NSUP + c) << 12) + entry];
    float run = 0.0f;
    #pragma unroll
    for (int c = 0; c < NSUP; ++c) {
      Sc[((size_t)(nh * NSUP + c) << 12) + entry] = (__bf16)run;
      run += (float)v[c];
    }
  } else {
    const int idx = (bid - NH * 16) * 256 + t;  // 0..2047
    const int nh = idx >> 6;
    const int e = idx & 63;
    __bf16 v[NCH64];
    #pragma unroll
    for (int c = 0; c < NCH64; ++c)
      v[c] = Ksc[((size_t)(nh * NCH64 + c) << 6) + e];
    float run = 0.0f;
    #pragma unroll
    for (int c = 0; c < NCH64; ++c) {
      Ksc[((size_t)(nh * NCH64 + c) << 6) + e] = (__bf16)run;
      run += (float)v[c];
    }
  }
}

// ================= Kernel 3: per-super-chunk output, 4 chunks with in-register state updates =================
#define P2_ISSUE(CC, BUF) { \
  const int l0i = (sc * GSUP + (CC)) * CHK; \
  _Pragma("unroll") for (int it = 0; it < 4; ++it) { \
    int f = t + 256 * it; int rr = f >> 4; int c4 = (f & 15) << 2; \
    size_t gb = (((size_t)n * LL + (size_t)(l0i + rr)) * HH + h) * EE + c4; \
    pk[BUF][it] = *(const float4*)(Kg + gb); \
    pv[BUF][it] = *(const float4*)(Vg + gb); \
    pl[BUF][it] = KLg[n * LL + l0i + rr]; } \
  { const float* qrow = Qg + (((size_t)n * LL + (size_t)(l0i + arow)) * HH + h) * EE; \
    pq[BUF][0] = *(const float4*)(qrow + 8 * lg); \
    pq[BUF][1] = *(const float4*)(qrow + 8 * lg + 4); \
    pq[BUF][2] = *(const float4*)(qrow + 32 + 8 * lg); \
    pq[BUF][3] = *(const float4*)(qrow + 32 + 8 * lg + 4); } }

#define P2_STAGE(BUF) { \
  _Pragma("unroll") for (int it = 0; it < 4; ++it) { \
    int f = t + 256 * it; int rr = f >> 4; int c4 = (f & 15) << 2; \
    float klr = pl[BUF][it]; float4 kk = pk[BUF][it]; float4 vv = pv[BUF][it]; \
    float ka[4] = {phi_map(kk.x) * klr, phi_map(kk.y) * klr, phi_map(kk.z) * klr, phi_map(kk.w) * klr}; \
    float va[4] = {vv.x, vv.y, vv.z, vv.w}; \
    __bf16* kd = &sK[BUF][rr][c4]; \
    kd[0] = (__bf16)ka[0]; kd[1] = (__bf16)ka[1]; kd[2] = (__bf16)ka[2]; kd[3] = (__bf16)ka[3]; \
    _Pragma("unroll") for (int jj = 0; jj < 4; ++jj) { \
      sKt[BUF][swz64(c4 + jj, rr)] = (__bf16)ka[jj]; \
      sVt[BUF][swz64(c4 + jj, rr)] = (__bf16)va[jj]; } } }

__global__ __launch_bounds__(256, 2) void k_pass2(
    const float* __restrict__ Qg, const float* __restrict__ Kg,
    const float* __restrict__ Vg, const float* __restrict__ KLg,
    const __bf16* __restrict__ Sp, const __bf16* __restrict__ Ksp,
    float* __restrict__ Og)
{
  __shared__ __bf16 sK[2][64][72];   // phi(K)*kl row-major [d][e]   (attn B)
  __shared__ __bf16 sKt[2][4096];    // K^T [e][d] swizzled          (state-update B)
  __shared__ __bf16 sVt[2][4096];    // V^T [m][d] swizzled          (PV / state-update A)
  __shared__ __bf16 sU[4608];        // S^T [m][e] stride 72; P overlay between inter and state-write

  const int g = blockIdx.x;          // nh*NSUP + sc
  const int sc = g % NSUP;
  const int nh = g / NSUP;
  const int h = nh % HH;
  const int n = nh / HH;
  const int t = threadIdx.x;
  const int w = t >> 6;
  const int lane = t & 63;
  const int lg = lane >> 4;
  const int li = lane & 15;
  const int arow = 16 * w + li;

  float4 pk[2][4], pv[2][4], pq[2][4];
  float pl[2][4];

  // ---- stage S^T super-prefix into sU ----
  {
    const bf16x8* sp8 = (const bf16x8*)(Sp + (size_t)g * 4096);
    bf16x8 s0 = sp8[2 * t];
    bf16x8 s1 = sp8[2 * t + 1];
    int m = t >> 2;
    int e0 = (t & 3) * 16;
    *(bf16x8*)&sU[m * 72 + e0] = s0;
    *(bf16x8*)&sU[m * 72 + e0 + 8] = s1;
  }

  P2_ISSUE(0, 0);
  P2_STAGE(0);

  float bSp[4][4];
  f32x4 accS[4];
  #pragma unroll
  for (int nt = 0; nt < 4; ++nt) accS[nt] = (f32x4){0.f, 0.f, 0.f, 0.f};

  #pragma unroll
  for (int cc = 0; cc < GSUP; ++cc) {
    __syncthreads();   // staging(cc) + state-writes(cc-1) visible everywhere

    if (cc == 0) {
      // base S^T in C-fragment positions (for state reconstruction)
      #pragma unroll
      for (int nt = 0; nt < 4; ++nt)
        #pragma unroll
        for (int reg = 0; reg < 4; ++reg)
          bSp[nt][reg] = (float)sU[(16 * w + 4 * lg + reg) * 72 + 16 * nt + li];
    }

    if (cc + 1 < GSUP) P2_ISSUE(cc + 1, (cc + 1) & 1);

    // ---- Q fragments (phi on prefetched regs) ----
    bf16x8 aQ0, aQ1;
    {
      float4 q0 = pq[cc & 1][0], q1 = pq[cc & 1][1], q2 = pq[cc & 1][2], q3 = pq[cc & 1][3];
      aQ0[0] = (__bf16)phi_map(q0.x); aQ0[1] = (__bf16)phi_map(q0.y);
      aQ0[2] = (__bf16)phi_map(q0.z); aQ0[3] = (__bf16)phi_map(q0.w);
      aQ0[4] = (__bf16)phi_map(q1.x); aQ0[5] = (__bf16)phi_map(q1.y);
      aQ0[6] = (__bf16)phi_map(q1.z); aQ0[7] = (__bf16)phi_map(q1.w);
      aQ1[0] = (__bf16)phi_map(q2.x); aQ1[1] = (__bf16)phi_map(q2.y);
      aQ1[2] = (__bf16)phi_map(q2.z); aQ1[3] = (__bf16)phi_map(q2.w);
      aQ1[4] = (__bf16)phi_map(q3.x); aQ1[5] = (__bf16)phi_map(q3.y);
      aQ1[6] = (__bf16)phi_map(q3.z); aQ1[7] = (__bf16)phi_map(q3.w);
    }

    // ---- ksum_prefix (64-chunk granularity) for denominator ----
    const __bf16* kb = Ksp + (size_t)(g * GSUP + cc) * 64;
    bf16x8 ks0 = *(const bf16x8*)(kb + 8 * lg);
    bf16x8 ks1 = *(const bf16x8*)(kb + 32 + 8 * lg);

    // ---- inter: acc = Q * S ----
    f32x4 acc[4];
    #pragma unroll
    for (int nt = 0; nt < 4; ++nt) acc[nt] = (f32x4){0.f, 0.f, 0.f, 0.f};
    #pragma unroll
    for (int nt = 0; nt < 4; ++nt) {
      bf16x8 b0 = *(const bf16x8*)&sU[(li + 16 * nt) * 72 + 8 * lg];
      bf16x8 b1 = *(const bf16x8*)&sU[(li + 16 * nt) * 72 + 32 + 8 * lg];
      acc[nt] = MFMA(aQ0, b0, acc[nt]);
      acc[nt] = MFMA(aQ1, b1, acc[nt]);
    }

    // ---- den = q . ksum_prefix (VALU + shfl) ----
    float dv = 0.0f;
    #pragma unroll
    for (int i = 0; i < 8; ++i) {
      dv += (float)aQ0[i] * (float)ks0[i];
      dv += (float)aQ1[i] * (float)ks1[i];
    }
    dv += __shfl_xor(dv, 16);
    dv += __shfl_xor(dv, 32);
    float den[4];
    #pragma unroll
    for (int reg = 0; reg < 4; ++reg) den[reg] = __shfl(dv, 4 * lg + reg);

    __syncthreads();   // all inter reads of sU done -> P may overlay

    // ---- intra: masked attn, P -> own sU rows ----
    float rs[4] = {0.f, 0.f, 0.f, 0.f};
    #pragma unroll
    for (int nt = 0; nt < 4; ++nt) {
      f32x4 at2 = (f32x4){0.f, 0.f, 0.f, 0.f};
      if (nt <= w) {
        bf16x8 b0 = *(const bf16x8*)&sK[cc & 1][li + 16 * nt][8 * lg];
        bf16x8 b1 = *(const bf16x8*)&sK[cc & 1][li + 16 * nt][32 + 8 * lg];
        at2 = MFMA(aQ0, b0, at2);
        at2 = MFMA(aQ1, b1, at2);
      }
      #pragma unroll
      for (int reg = 0; reg < 4; ++reg) {
        int row = 16 * w + 4 * lg + reg;
        int col = li + 16 * nt;
        float av = (col <= row) ? at2[reg] : 0.0f;
        rs[reg] += av;
        sU[w * 1152 + (4 * lg + reg) * 72 + col] = (__bf16)av;
      }
    }

    // ---- PV: acc += P * V ----
    {
      bf16x8 aA0 = *(const bf16x8*)&sU[w * 1152 + li * 72 + 8 * lg];
      bf16x8 aA1 = aA0;
      if (w >= 2) aA1 = *(const bf16x8*)&sU[w * 1152 + li * 72 + 32 + 8 * lg];
      #pragma unroll
      for (int nt = 0; nt < 4; ++nt) {
        bf16x8 bv0 = *(const bf16x8*)&sVt[cc & 1][frag64(li + 16 * nt, lg)];
        acc[nt] = MFMA(aA0, bv0, acc[nt]);
        if (w >= 2) {
          bf16x8 bv1 = *(const bf16x8*)&sVt[cc & 1][frag64(li + 16 * nt, 4 + lg)];
          acc[nt] = MFMA(aA1, bv1, acc[nt]);
        }
      }
    }

    // ---- rowsum reduce ----
    #pragma unroll
    for (int reg = 0; reg < 4; ++reg) {
      float v = rs[reg];
      v += __shfl_xor(v, 1);
      v += __shfl_xor(v, 2);
      v += __shfl_xor(v, 4);
      v += __shfl_xor(v, 8);
      rs[reg] = v;
    }

    // ---- normalize + store ----
    const int l0 = (sc * GSUP + cc) * CHK;
    #pragma unroll
    for (int reg = 0; reg < 4; ++reg) {
      float inv = 1.0f / (den[reg] + rs[reg] + EPSF);
      int row = l0 + 16 * w + 4 * lg + reg;
      size_t ob = (((size_t)n * LL + row) * HH + h) * EE + li;
      #pragma unroll
      for (int nt = 0; nt < 4; ++nt)
        Og[ob + 16 * nt] = acc[nt][reg] * inv;
    }

    // ---- state update + rebuild sU own rows; stage next chunk ----
    if (cc + 1 < GSUP) {
      bf16x8 aV0 = *(const bf16x8*)&sVt[cc & 1][frag64(16 * w + li, lg)];
      bf16x8 aV1 = *(const bf16x8*)&sVt[cc & 1][frag64(16 * w + li, 4 + lg)];
      #pragma unroll
      for (int nt = 0; nt < 4; ++nt) {
        bf16x8 b0 = *(const bf16x8*)&sKt[cc & 1][frag64(li + 16 * nt, lg)];
        bf16x8 b1 = *(const bf16x8*)&sKt[cc & 1][frag64(li + 16 * nt, 4 + lg)];
        accS[nt] = MFMA(aV0, b0, accS[nt]);
        accS[nt] = MFMA(aV1, b1, accS[nt]);
      }
      #pragma unroll
      for (int nt = 0; nt < 4; ++nt)
        #pragma unroll
        for (int reg = 0; reg < 4; ++reg)
          sU[(16 * w + 4 * lg + reg) * 72 + 16 * nt + li] =
            (__bf16)(bSp[nt][reg] + accS[nt][reg]);

      P2_STAGE((cc + 1) & 1);
    }
  }
}

extern "C" void kernel_launch(void* const* d_in, const int* in_sizes, int n_in,
                              void* d_out, int out_size, void* d_ws, size_t ws_size,
                              hipStream_t stream) {
  const float* Qg  = (const float*)d_in[0];
  const float* Kg  = (const float*)d_in[1];
  const float* Vg  = (const float*)d_in[2];
  const float* KLg = (const float*)d_in[3];
  float* Og = (float*)d_out;

  // ws: Sc bf16 512*4096*2 = 4MB | Ksc bf16 2048*64*2 = 256KB (prefix in place)
  __bf16* Sc  = (__bf16*)d_ws;
  __bf16* Ksc = (__bf16*)((char*)d_ws + (size_t)NBLK * 4096 * 2);

  hipLaunchKernelGGL(k_chunksums, dim3(NBLK), dim3(256), 0, stream, Kg, Vg, KLg, Sc, Ksc);
  hipLaunchKernelGGL(k_prefix, dim3(NH * 16 + 8), dim3(256), 0, stream, Sc, Ksc);
  hipLaunchKernelGGL(k_pass2, dim3(NBLK), dim3(256), 0, stream, Qg, Kg, Vg, KLg, Sc, Ksc, Og);
}